// Round 3
// baseline (481.286 us; speedup 1.0000x reference)
//
#include <hip/hip_runtime.h>
#include <cmath>
#include <cstdint>

// GCNConv(C=256 -> 1, add_self_loops, symmetric norm) + Softplus
//
// Key trick: device-scope fp32 atomics on MI355X execute at the cross-XCD
// coherent point (~18.8 G/s — measured R1/R2, WRITE_SIZE 32B/atomic). We
// instead keep 8 per-XCD replicas and issue raw `global_atomic_add_f32`
// (no sc1) via inline asm -> executes in the local XCD's L2. Dispatch-end
// L2 writeback makes replicas visible to the following reduction kernel.
//
//  memset: cnt[8][Np] = 0, acc[8][Np] = 0
//  K12: phase A: h[n] = dot(x[n,:], W)      (wave-per-row, float4)
//       phase B: cnt[xcd][dst[e]] += 1.0f   (L2-local f32 atomics)
//  K3 : deg = 1 + sum_r cnt[r][n]; dinv = rsqrt(deg); g = dinv*h -> h;
//       acc[0][n] = g (self-loop seed)
//  K4 : acc[xcd][dst[e]] += g[src[e]]       (L2-local f32 atomics)
//  K5 : out[n] = softplus(dinv[n] * sum_r acc[r][n] + b)

#define NREP 8

__device__ __forceinline__ unsigned xccId() {
    unsigned x;
    asm volatile("s_getreg_b32 %0, hwreg(HW_REG_XCC_ID)" : "=s"(x));
    return x & 7u;
}

// L2-local (no sc1) fire-and-forget fp32 atomic add.
__device__ __forceinline__ void l2AtomicAddF32(float* p, float v) {
    asm volatile("global_atomic_add_f32 %0, %1, off"
                 :: "v"((uint64_t)(uintptr_t)p), "v"(v)
                 : "memory");
}

__global__ __launch_bounds__(256) void k12_dot_hist(
        const float* __restrict__ x,
        const float* __restrict__ W,
        const int* __restrict__ dst,
        float* __restrict__ h,
        float* __restrict__ cnt,     // [NREP][Np]
        int N, int E, int Np) {
    int tid  = blockIdx.x * blockDim.x + threadIdx.x;
    int nthr = gridDim.x * blockDim.x;
    int lane = threadIdx.x & 63;

    // ---- phase A: wave-per-row dot(x[row,:], W) ----
    const float4 wv = *reinterpret_cast<const float4*>(W + lane * 4);
    int nwaves = nthr >> 6;
    for (int row = tid >> 6; row < N; row += nwaves) {
        const float4 xv = *reinterpret_cast<const float4*>(x + (size_t)row * 256 + lane * 4);
        float s = xv.x * wv.x + xv.y * wv.y + xv.z * wv.z + xv.w * wv.w;
        #pragma unroll
        for (int off = 32; off >= 1; off >>= 1)
            s += __shfl_xor(s, off, 64);
        if (lane == 0) h[row] = s;
    }

    // ---- phase B: degree histogram into this XCD's replica ----
    float* myCnt = cnt + (size_t)xccId() * Np;
    int E4 = E >> 2;
    const int4* d4 = reinterpret_cast<const int4*>(dst);
    for (int i = tid; i < E4; i += nthr) {
        int4 v = d4[i];
        l2AtomicAddF32(&myCnt[v.x], 1.0f);
        l2AtomicAddF32(&myCnt[v.y], 1.0f);
        l2AtomicAddF32(&myCnt[v.z], 1.0f);
        l2AtomicAddF32(&myCnt[v.w], 1.0f);
    }
    for (int i = (E4 << 2) + tid; i < E; i += nthr)
        l2AtomicAddF32(&myCnt[dst[i]], 1.0f);

    asm volatile("s_waitcnt vmcnt(0)" ::: "memory");
}

__global__ __launch_bounds__(256) void k3_prep(
        const float* __restrict__ cnt,   // [NREP][Np]
        float* __restrict__ h,           // in: dot, out: g = dinv*h
        float* __restrict__ dinv,
        float* __restrict__ acc,         // [NREP][Np]; rep0 seeded here
        int N, int Np) {
    int n = blockIdx.x * blockDim.x + threadIdx.x;
    if (n >= N) return;
    float deg = 1.0f;   // self-loop
    #pragma unroll
    for (int r = 0; r < NREP; ++r)
        deg += cnt[(size_t)r * Np + n];
    float di = rsqrtf(deg);
    float g  = di * h[n];
    dinv[n] = di;
    h[n]    = g;
    acc[n]  = g;        // replica 0 seed; replicas 1..7 zeroed by memset
}

__global__ __launch_bounds__(256) void k4_scatter(
        const int* __restrict__ src,
        const int* __restrict__ dst,
        const float* __restrict__ g,
        float* __restrict__ acc,         // [NREP][Np]
        int E, int Np) {
    int tid  = blockIdx.x * blockDim.x + threadIdx.x;
    int nthr = gridDim.x * blockDim.x;
    float* myAcc = acc + (size_t)xccId() * Np;
    int E4 = E >> 2;
    const int4* s4 = reinterpret_cast<const int4*>(src);
    const int4* d4 = reinterpret_cast<const int4*>(dst);
    for (int i = tid; i < E4; i += nthr) {
        int4 sv = s4[i];
        int4 dv = d4[i];
        float g0 = g[sv.x], g1 = g[sv.y], g2 = g[sv.z], g3 = g[sv.w];
        l2AtomicAddF32(&myAcc[dv.x], g0);
        l2AtomicAddF32(&myAcc[dv.y], g1);
        l2AtomicAddF32(&myAcc[dv.z], g2);
        l2AtomicAddF32(&myAcc[dv.w], g3);
    }
    for (int i = (E4 << 2) + tid; i < E; i += nthr)
        l2AtomicAddF32(&myAcc[dst[i]], g[src[i]]);

    asm volatile("s_waitcnt vmcnt(0)" ::: "memory");
}

__global__ __launch_bounds__(256) void k5_final(
        const float* __restrict__ dinv,
        const float* __restrict__ acc,   // [NREP][Np]
        const float* __restrict__ b,
        float* __restrict__ out, int N, int Np) {
    int n = blockIdx.x * blockDim.x + threadIdx.x;
    if (n >= N) return;
    float s = 0.0f;
    #pragma unroll
    for (int r = 0; r < NREP; ++r)
        s += acc[(size_t)r * Np + n];
    float v = dinv[n] * s + b[0];
    out[n] = fmaxf(v, 0.0f) + log1pf(expf(-fabsf(v)));   // stable softplus
}

extern "C" void kernel_launch(void* const* d_in, const int* in_sizes, int n_in,
                              void* d_out, int out_size, void* d_ws, size_t ws_size,
                              hipStream_t stream) {
    const float* x  = (const float*)d_in[0];
    const int*   ei = (const int*)d_in[1];
    const float* W  = (const float*)d_in[2];
    const float* b  = (const float*)d_in[3];
    float* out = (float*)d_out;

    int N = in_sizes[0] / 256;
    int E = in_sizes[1] / 2;
    const int* src = ei;
    const int* dst = ei + E;

    int Np = (N + 63) & ~63;                 // pad replica stride to 256 B

    float* h    = (float*)d_ws;              // N
    float* dinv = h + Np;                    // N
    float* acc  = dinv + Np;                 // NREP * Np
    float* cnt  = acc + (size_t)NREP * Np;   // NREP * Np

    hipMemsetAsync(acc, 0, (size_t)NREP * Np * sizeof(float), stream);
    hipMemsetAsync(cnt, 0, (size_t)NREP * Np * sizeof(float), stream);

    k12_dot_hist<<<2048, 256, 0, stream>>>(x, W, dst, h, cnt, N, E, Np);

    int blocksN = (N + 255) / 256;
    k3_prep<<<blocksN, 256, 0, stream>>>(cnt, h, dinv, acc, N, Np);

    k4_scatter<<<2048, 256, 0, stream>>>(src, dst, h, acc, E, Np);

    k5_final<<<blocksN, 256, 0, stream>>>(dinv, acc, b, out, N, Np);
}

// Round 4
// 303.543 us; speedup vs baseline: 1.5856x; 1.5856x over previous
//
#include <hip/hip_runtime.h>
#include <cmath>
#include <cstdint>

// GCNConv(C=256 -> 1, add_self_loops, symmetric norm) + Softplus
//
// R1-R3 lesson: scatter global atomics on gfx950 execute memory-side
// (~19 G/s, 32 B HBM write-through each) regardless of scope/cache bits.
// => atomic-FREE pipeline via counting sort by dst bucket + LDS aggregation.
//
//  K_dot  : h[n] = dot(x[n,:], W)                (wave-per-row, float4)
//  K_count: counts[block][bucket] over dst        (LDS hist, plain stores)
//  K_scan : exact exclusive scan -> blockBase[block][bucket] (1 block)
//  K_part : sorted[pos] = (dst&255)<<17 | src     (base + LDS rank, no atomics)
//  K_deg  : per-bucket LDS u32 hist -> dinv, g=dinv*h
//  K_agg  : per-bucket LDS f32 acc of g[src] -> softplus -> out

#define NBSHIFT 8                    // 256 nodes per bucket
#define NLOCAL  (1 << NBSHIFT)
#define KPART   256                  // chunking blocks for count/partition
#define SRCBITS 17                   // N=100000 < 2^17

__global__ __launch_bounds__(256) void k_dot(const float* __restrict__ x,
                                             const float* __restrict__ W,
                                             float* __restrict__ h, int N) {
    int tid  = blockIdx.x * blockDim.x + threadIdx.x;
    int lane = threadIdx.x & 63;
    int nw   = (gridDim.x * blockDim.x) >> 6;
    const float4 wv = *reinterpret_cast<const float4*>(W + lane * 4);
    for (int row = tid >> 6; row < N; row += nw) {
        const float4 xv = *reinterpret_cast<const float4*>(x + (size_t)row * 256 + lane * 4);
        float s = xv.x * wv.x + xv.y * wv.y + xv.z * wv.z + xv.w * wv.w;
        #pragma unroll
        for (int o = 32; o >= 1; o >>= 1) s += __shfl_xor(s, o, 64);
        if (lane == 0) h[row] = s;
    }
}

__global__ __launch_bounds__(256) void k_count(const int* __restrict__ dst,
                                               unsigned* __restrict__ counts, // [KPART][NB]
                                               int E, int NB, int CH) {
    __shared__ unsigned cnt[512];
    for (int j = threadIdx.x; j < NB; j += 256) cnt[j] = 0;
    __syncthreads();
    int s = blockIdx.x * CH, e = min(E, s + CH);
    for (int i = s + threadIdx.x; i < e; i += 256)
        atomicAdd(&cnt[((unsigned)dst[i]) >> NBSHIFT], 1u);
    __syncthreads();
    unsigned* row = counts + (size_t)blockIdx.x * NB;
    for (int j = threadIdx.x; j < NB; j += 256) row[j] = cnt[j];
}

__global__ __launch_bounds__(512) void k_scan(const unsigned* __restrict__ counts,   // [KPART][NB]
                                              unsigned* __restrict__ blockBase,      // [KPART][NB]
                                              int NB) {
    __shared__ unsigned tot[512];
    int j = threadIdx.x;
    unsigned t = 0;
    if (j < NB)
        for (int b = 0; b < KPART; ++b) t += counts[(size_t)b * NB + j];
    tot[j] = t;
    __syncthreads();
    // inclusive Hillis-Steele scan over 512 slots
    for (int off = 1; off < 512; off <<= 1) {
        unsigned add = (j >= off) ? tot[j - off] : 0u;
        __syncthreads();
        tot[j] += add;
        __syncthreads();
    }
    unsigned run = tot[j] - t;   // exclusive bucket base
    if (j < NB)
        for (int b = 0; b < KPART; ++b) {
            unsigned c = counts[(size_t)b * NB + j];
            blockBase[(size_t)b * NB + j] = run;
            run += c;
        }
}

__global__ __launch_bounds__(256) void k_part(const int* __restrict__ src,
                                              const int* __restrict__ dst,
                                              const unsigned* __restrict__ blockBase,
                                              unsigned* __restrict__ sorted,
                                              int E, int NB, int CH) {
    __shared__ unsigned base[512];
    __shared__ unsigned rank[512];
    for (int j = threadIdx.x; j < NB; j += 256) {
        base[j] = blockBase[(size_t)blockIdx.x * NB + j];
        rank[j] = 0;
    }
    __syncthreads();
    int s = blockIdx.x * CH, e = min(E, s + CH);
    for (int i = s + threadIdx.x; i < e; i += 256) {
        unsigned d = (unsigned)dst[i];
        unsigned j = d >> NBSHIFT;
        unsigned r = atomicAdd(&rank[j], 1u);          // LDS atomic only
        sorted[base[j] + r] = ((d & (NLOCAL - 1u)) << SRCBITS) | (unsigned)src[i];
    }
}

__global__ __launch_bounds__(256) void k_deg(const unsigned* __restrict__ sorted,
                                             const unsigned* __restrict__ bucketBase, // blockBase row 0
                                             const float* __restrict__ h,
                                             float* __restrict__ dinv,
                                             float* __restrict__ g,
                                             int E, int N, int NB) {
    __shared__ unsigned acc[NLOCAL];
    acc[threadIdx.x] = 0;
    __syncthreads();
    int j = blockIdx.x;
    unsigned s0 = bucketBase[j];
    unsigned e0 = (j + 1 < NB) ? bucketBase[j + 1] : (unsigned)E;
    for (unsigned i = s0 + threadIdx.x; i < e0; i += 256)
        atomicAdd(&acc[sorted[i] >> SRCBITS], 1u);     // LDS atomic only
    __syncthreads();
    int n = (j << NBSHIFT) + threadIdx.x;
    if (n < N) {
        float di = rsqrtf((float)(acc[threadIdx.x] + 1u));  // +1 self-loop
        dinv[n] = di;
        g[n]    = di * h[n];
    }
}

__global__ __launch_bounds__(256) void k_agg(const unsigned* __restrict__ sorted,
                                             const unsigned* __restrict__ bucketBase,
                                             const float* __restrict__ g,
                                             const float* __restrict__ dinv,
                                             const float* __restrict__ b,
                                             float* __restrict__ out,
                                             int E, int N, int NB) {
    __shared__ float acc[NLOCAL];
    acc[threadIdx.x] = 0.0f;
    __syncthreads();
    int j = blockIdx.x;
    unsigned s0 = bucketBase[j];
    unsigned e0 = (j + 1 < NB) ? bucketBase[j + 1] : (unsigned)E;
    for (unsigned i = s0 + threadIdx.x; i < e0; i += 256) {
        unsigned p = sorted[i];
        atomicAdd(&acc[p >> SRCBITS], g[p & ((1u << SRCBITS) - 1u)]);  // LDS f32 atomic
    }
    __syncthreads();
    int n = (j << NBSHIFT) + threadIdx.x;
    if (n < N) {
        float v = dinv[n] * (acc[threadIdx.x] + g[n]) + b[0];
        out[n] = fmaxf(v, 0.0f) + log1pf(expf(-fabsf(v)));  // stable softplus
    }
}

extern "C" void kernel_launch(void* const* d_in, const int* in_sizes, int n_in,
                              void* d_out, int out_size, void* d_ws, size_t ws_size,
                              hipStream_t stream) {
    const float* x  = (const float*)d_in[0];
    const int*   ei = (const int*)d_in[1];
    const float* W  = (const float*)d_in[2];
    const float* b  = (const float*)d_in[3];
    float* out = (float*)d_out;

    int N = in_sizes[0] / 256;
    int E = in_sizes[1] / 2;
    const int* src = ei;
    const int* dst = ei + E;

    int NB = (N + NLOCAL - 1) >> NBSHIFT;     // 391 buckets
    int CH = (E + KPART - 1) / KPART;         // edges per partition block

    float*    h      = (float*)d_ws;                       // N
    float*    dinv   = h + N;                              // N
    float*    g      = dinv + N;                           // N
    unsigned* sorted = (unsigned*)(g + N);                 // E
    unsigned* counts = sorted + E;                         // KPART*NB
    unsigned* bbase  = counts + (size_t)KPART * NB;        // KPART*NB

    k_dot  <<<2048, 256, 0, stream>>>(x, W, h, N);
    k_count<<<KPART, 256, 0, stream>>>(dst, counts, E, NB, CH);
    k_scan <<<1, 512, 0, stream>>>(counts, bbase, NB);
    k_part <<<KPART, 256, 0, stream>>>(src, dst, bbase, sorted, E, NB, CH);
    k_deg  <<<NB, 256, 0, stream>>>(sorted, bbase, h, dinv, g, E, N, NB);
    k_agg  <<<NB, 256, 0, stream>>>(sorted, bbase, g, dinv, b, out, E, N, NB);
}

// Round 5
// 248.779 us; speedup vs baseline: 1.9346x; 1.2201x over previous
//
#include <hip/hip_runtime.h>
#include <cmath>
#include <cstdint>

// GCNConv(C=256 -> 1, add_self_loops, symmetric norm) + Softplus
//
// Atomic-free pipeline (R1-R3: gfx950 scatter global atomics run memory-side,
// ~19 G/s, 32 B HBM write-through each — unusable). Counting sort by dst
// bucket (256 nodes/bucket) + per-bucket LDS aggregation.
//
//  k_dot  : h[n] = dot(x[n,:], W)            wave-per-row, float4 (HBM-bound)
//  k_count: countsT[bucket][block] LDS hist over dst chunks (1024 blocks)
//  k_scanA: bucketTot[j] = sum_b countsT[j][b]          (NB blocks)
//  k_scanB: bucketBase[j] = exclusive scan of bucketTot (1 block, tiny)
//  k_scanC: baseT[j][b] = bucketBase[j] + prefix_b      (NB blocks, parallel)
//  k_part : sorted[pos] = (dst&255)<<17 | src  (LDS rank atomics only)
//  k_deg  : per-bucket LDS u32 hist -> dinv, g = dinv*h
//  k_agg  : per-bucket LDS f32 acc of g[src] + self-loop -> softplus -> out

#define NBSHIFT 8
#define NLOCAL  (1 << NBSHIFT)     // 256 nodes per bucket
#define KPART   1024               // chunking blocks for count/partition
#define SRCBITS 17                 // N=100000 < 2^17

__global__ __launch_bounds__(256) void k_dot(const float* __restrict__ x,
                                             const float* __restrict__ W,
                                             float* __restrict__ h, int N) {
    int tid  = blockIdx.x * blockDim.x + threadIdx.x;
    int lane = threadIdx.x & 63;
    int nw   = (gridDim.x * blockDim.x) >> 6;
    const float4 wv = *reinterpret_cast<const float4*>(W + lane * 4);
    for (int row = tid >> 6; row < N; row += nw) {
        const float4 xv = *reinterpret_cast<const float4*>(x + (size_t)row * 256 + lane * 4);
        float s = xv.x * wv.x + xv.y * wv.y + xv.z * wv.z + xv.w * wv.w;
        #pragma unroll
        for (int o = 32; o >= 1; o >>= 1) s += __shfl_xor(s, o, 64);
        if (lane == 0) h[row] = s;
    }
}

__global__ __launch_bounds__(256) void k_count(const int* __restrict__ dst,
                                               unsigned* __restrict__ countsT, // [NB][KPART]
                                               int E, int NB, int CH) {
    __shared__ unsigned cnt[512];
    for (int j = threadIdx.x; j < 512; j += 256) cnt[j] = 0;
    __syncthreads();
    int s = blockIdx.x * CH, e = min(E, s + CH);
    int e4 = s + (((e - s) >> 2) << 2);
    for (int i = s + (int)threadIdx.x * 4; i < e4; i += 1024) {
        int4 v = *reinterpret_cast<const int4*>(dst + i);
        atomicAdd(&cnt[((unsigned)v.x) >> NBSHIFT], 1u);
        atomicAdd(&cnt[((unsigned)v.y) >> NBSHIFT], 1u);
        atomicAdd(&cnt[((unsigned)v.z) >> NBSHIFT], 1u);
        atomicAdd(&cnt[((unsigned)v.w) >> NBSHIFT], 1u);
    }
    for (int i = e4 + threadIdx.x; i < e; i += 256)
        atomicAdd(&cnt[((unsigned)dst[i]) >> NBSHIFT], 1u);
    __syncthreads();
    for (int j = threadIdx.x; j < NB; j += 256)
        countsT[(size_t)j * KPART + blockIdx.x] = cnt[j];
}

__global__ __launch_bounds__(256) void k_scanA(const unsigned* __restrict__ countsT,
                                               unsigned* __restrict__ bucketTot) {
    __shared__ unsigned red[256];
    int j = blockIdx.x, t = threadIdx.x;
    uint4 c = *reinterpret_cast<const uint4*>(countsT + (size_t)j * KPART + t * 4);
    red[t] = c.x + c.y + c.z + c.w;
    __syncthreads();
    for (int s = 128; s > 0; s >>= 1) {
        if (t < s) red[t] += red[t + s];
        __syncthreads();
    }
    if (t == 0) bucketTot[j] = red[0];
}

__global__ __launch_bounds__(512) void k_scanB(const unsigned* __restrict__ bucketTot,
                                               unsigned* __restrict__ bucketBase,
                                               int NB) {
    __shared__ unsigned arr[512];
    int t = threadIdx.x;
    unsigned own = (t < NB) ? bucketTot[t] : 0u;
    arr[t] = own;
    __syncthreads();
    for (int off = 1; off < 512; off <<= 1) {
        unsigned add = (t >= off) ? arr[t - off] : 0u;
        __syncthreads();
        arr[t] += add;
        __syncthreads();
    }
    if (t < NB) bucketBase[t] = arr[t] - own;       // exclusive
    if (t == NB - 1) bucketBase[NB] = arr[t];       // total = E
}

__global__ __launch_bounds__(256) void k_scanC(const unsigned* __restrict__ countsT,
                                               const unsigned* __restrict__ bucketBase,
                                               unsigned* __restrict__ baseT) { // [NB][KPART]
    __shared__ unsigned arr[256];
    int j = blockIdx.x, t = threadIdx.x;
    uint4 c = *reinterpret_cast<const uint4*>(countsT + (size_t)j * KPART + t * 4);
    unsigned own = c.x + c.y + c.z + c.w;
    arr[t] = own;
    __syncthreads();
    for (int off = 1; off < 256; off <<= 1) {
        unsigned add = (t >= off) ? arr[t - off] : 0u;
        __syncthreads();
        arr[t] += add;
        __syncthreads();
    }
    unsigned base = bucketBase[j] + (arr[t] - own);  // exclusive across threads
    uint4 o;
    o.x = base;
    o.y = base + c.x;
    o.z = base + c.x + c.y;
    o.w = base + c.x + c.y + c.z;
    *reinterpret_cast<uint4*>(baseT + (size_t)j * KPART + t * 4) = o;
}

__global__ __launch_bounds__(256) void k_part(const int* __restrict__ src,
                                              const int* __restrict__ dst,
                                              const unsigned* __restrict__ baseT,
                                              unsigned* __restrict__ sorted,
                                              int E, int NB, int CH) {
    __shared__ unsigned base[512];
    __shared__ unsigned rank[512];
    for (int j = threadIdx.x; j < NB; j += 256) {
        base[j] = baseT[(size_t)j * KPART + blockIdx.x];
        rank[j] = 0;
    }
    __syncthreads();
    int s = blockIdx.x * CH, e = min(E, s + CH);
    int e4 = s + (((e - s) >> 2) << 2);
    for (int i = s + (int)threadIdx.x * 4; i < e4; i += 1024) {
        int4 dv = *reinterpret_cast<const int4*>(dst + i);
        int4 sv = *reinterpret_cast<const int4*>(src + i);
        unsigned d, j, r;
        d = (unsigned)dv.x; j = d >> NBSHIFT; r = atomicAdd(&rank[j], 1u);
        sorted[base[j] + r] = ((d & (NLOCAL - 1u)) << SRCBITS) | (unsigned)sv.x;
        d = (unsigned)dv.y; j = d >> NBSHIFT; r = atomicAdd(&rank[j], 1u);
        sorted[base[j] + r] = ((d & (NLOCAL - 1u)) << SRCBITS) | (unsigned)sv.y;
        d = (unsigned)dv.z; j = d >> NBSHIFT; r = atomicAdd(&rank[j], 1u);
        sorted[base[j] + r] = ((d & (NLOCAL - 1u)) << SRCBITS) | (unsigned)sv.z;
        d = (unsigned)dv.w; j = d >> NBSHIFT; r = atomicAdd(&rank[j], 1u);
        sorted[base[j] + r] = ((d & (NLOCAL - 1u)) << SRCBITS) | (unsigned)sv.w;
    }
    for (int i = e4 + threadIdx.x; i < e; i += 256) {
        unsigned d = (unsigned)dst[i];
        unsigned j = d >> NBSHIFT;
        unsigned r = atomicAdd(&rank[j], 1u);
        sorted[base[j] + r] = ((d & (NLOCAL - 1u)) << SRCBITS) | (unsigned)src[i];
    }
}

__global__ __launch_bounds__(512) void k_deg(const unsigned* __restrict__ sorted,
                                             const unsigned* __restrict__ bucketBase,
                                             const float* __restrict__ h,
                                             float* __restrict__ dinv,
                                             float* __restrict__ g,
                                             int N) {
    __shared__ unsigned acc[NLOCAL];
    int j = blockIdx.x, t = threadIdx.x;
    if (t < NLOCAL) acc[t] = 0;
    __syncthreads();
    unsigned s0 = bucketBase[j], e0 = bucketBase[j + 1];
    for (unsigned i = s0 + t; i < e0; i += 512)
        atomicAdd(&acc[sorted[i] >> SRCBITS], 1u);
    __syncthreads();
    if (t < NLOCAL) {
        int n = (j << NBSHIFT) + t;
        if (n < N) {
            float di = rsqrtf((float)(acc[t] + 1u));   // +1 self-loop
            dinv[n] = di;
            g[n]    = di * h[n];
        }
    }
}

__global__ __launch_bounds__(512) void k_agg(const unsigned* __restrict__ sorted,
                                             const unsigned* __restrict__ bucketBase,
                                             const float* __restrict__ g,
                                             const float* __restrict__ dinv,
                                             const float* __restrict__ b,
                                             float* __restrict__ out,
                                             int N) {
    __shared__ float acc[NLOCAL];
    int j = blockIdx.x, t = threadIdx.x;
    if (t < NLOCAL) acc[t] = 0.0f;
    __syncthreads();
    unsigned s0 = bucketBase[j], e0 = bucketBase[j + 1];
    for (unsigned i = s0 + t; i < e0; i += 512) {
        unsigned p = sorted[i];
        atomicAdd(&acc[p >> SRCBITS], g[p & ((1u << SRCBITS) - 1u)]);
    }
    __syncthreads();
    if (t < NLOCAL) {
        int n = (j << NBSHIFT) + t;
        if (n < N) {
            float v = dinv[n] * (acc[t] + g[n]) + b[0];
            out[n] = fmaxf(v, 0.0f) + log1pf(expf(-fabsf(v)));  // stable softplus
        }
    }
}

extern "C" void kernel_launch(void* const* d_in, const int* in_sizes, int n_in,
                              void* d_out, int out_size, void* d_ws, size_t ws_size,
                              hipStream_t stream) {
    const float* x  = (const float*)d_in[0];
    const int*   ei = (const int*)d_in[1];
    const float* W  = (const float*)d_in[2];
    const float* b  = (const float*)d_in[3];
    float* out = (float*)d_out;

    int N = in_sizes[0] / 256;
    int E = in_sizes[1] / 2;
    const int* src = ei;
    const int* dst = ei + E;

    int NB = (N + NLOCAL - 1) >> NBSHIFT;                 // 391
    int CH = (((E + KPART - 1) / KPART) + 3) & ~3;        // multiple of 4

    float*    h       = (float*)d_ws;                     // N
    float*    dinv    = h + N;                            // N
    float*    g       = dinv + N;                         // N
    unsigned* sorted  = (unsigned*)(g + N);               // E
    unsigned* countsT = sorted + E;                       // NB*KPART
    unsigned* baseT   = countsT + (size_t)NB * KPART;     // NB*KPART
    unsigned* btot    = baseT + (size_t)NB * KPART;       // NB
    unsigned* bbase   = btot + NB;                        // NB+1

    k_dot  <<<2048, 256, 0, stream>>>(x, W, h, N);
    k_count<<<KPART, 256, 0, stream>>>(dst, countsT, E, NB, CH);
    k_scanA<<<NB, 256, 0, stream>>>(countsT, btot);
    k_scanB<<<1, 512, 0, stream>>>(btot, bbase, NB);
    k_scanC<<<NB, 256, 0, stream>>>(countsT, bbase, baseT);
    k_part <<<KPART, 256, 0, stream>>>(src, dst, baseT, sorted, E, NB, CH);
    k_deg  <<<NB, 512, 0, stream>>>(sorted, bbase, h, dinv, g, N);
    k_agg  <<<NB, 512, 0, stream>>>(sorted, bbase, g, dinv, b, out, N);
}

// Round 6
// 238.266 us; speedup vs baseline: 2.0200x; 1.0441x over previous
//
#include <hip/hip_runtime.h>
#include <cmath>
#include <cstdint>

// GCNConv(C=256 -> 1, add_self_loops, symmetric norm) + Softplus
//
// Atomic-free pipeline (R1-R3: gfx950 scatter global atomics run memory-side,
// ~19 G/s, 32 B HBM write-through each — unusable). Counting sort by dst
// bucket (256 nodes/bucket) + per-bucket LDS aggregation.
//
//  k_front: h[n] = dot(x[n,:], W)  (wave-per-row)  FUSED WITH
//           countsT[bucket][block] LDS hist over dst chunk
//  k_scanA: btot[j] = sum_b countsT[j][b]              (NB blocks)
//  k_scanC: bbase[j] (self-computed masked reduce of btot) +
//           baseT[j][b] = bbase[j] + prefix_b          (NB blocks)
//  k_part : sorted[pos] = (dst&255)<<17 | src          (LDS rank atomics)
//  k_deg  : per-bucket LDS u32 hist -> dinv, g = dinv*h  (1024 thr)
//  k_agg  : per-bucket LDS f32 acc of g[src] -> softplus  (1024 thr)

#define NBSHIFT 8
#define NLOCAL  (1 << NBSHIFT)     // 256 nodes per bucket
#define KPART   1024               // chunk blocks for count/partition
#define SRCBITS 17                 // N=100000 < 2^17

__global__ __launch_bounds__(256) void k_front(const float* __restrict__ x,
                                               const float* __restrict__ W,
                                               const int* __restrict__ dst,
                                               float* __restrict__ h,
                                               unsigned* __restrict__ countsT, // [NB][KPART]
                                               int N, int E, int NB, int CH) {
    // ---- phase A: wave-per-row dot(x[row,:], W) ----
    int tid  = blockIdx.x * blockDim.x + threadIdx.x;
    int lane = threadIdx.x & 63;
    int nw   = (gridDim.x * blockDim.x) >> 6;
    const float4 wv = *reinterpret_cast<const float4*>(W + lane * 4);
    for (int row = tid >> 6; row < N; row += nw) {
        const float4 xv = *reinterpret_cast<const float4*>(x + (size_t)row * 256 + lane * 4);
        float s = xv.x * wv.x + xv.y * wv.y + xv.z * wv.z + xv.w * wv.w;
        #pragma unroll
        for (int o = 32; o >= 1; o >>= 1) s += __shfl_xor(s, o, 64);
        if (lane == 0) h[row] = s;
    }

    // ---- phase B: per-chunk bucket histogram (LDS atomics only) ----
    __shared__ unsigned cnt[512];
    for (int j = threadIdx.x; j < 512; j += 256) cnt[j] = 0;
    __syncthreads();
    int s = blockIdx.x * CH, e = min(E, s + CH);
    int e4 = s + (((e - s) >> 2) << 2);
    for (int i = s + (int)threadIdx.x * 4; i < e4; i += 1024) {
        int4 v = *reinterpret_cast<const int4*>(dst + i);
        atomicAdd(&cnt[((unsigned)v.x) >> NBSHIFT], 1u);
        atomicAdd(&cnt[((unsigned)v.y) >> NBSHIFT], 1u);
        atomicAdd(&cnt[((unsigned)v.z) >> NBSHIFT], 1u);
        atomicAdd(&cnt[((unsigned)v.w) >> NBSHIFT], 1u);
    }
    for (int i = e4 + threadIdx.x; i < e; i += 256)
        atomicAdd(&cnt[((unsigned)dst[i]) >> NBSHIFT], 1u);
    __syncthreads();
    for (int j = threadIdx.x; j < NB; j += 256)
        countsT[(size_t)j * KPART + blockIdx.x] = cnt[j];
}

__global__ __launch_bounds__(256) void k_scanA(const unsigned* __restrict__ countsT,
                                               unsigned* __restrict__ btot) {
    __shared__ unsigned red[256];
    int j = blockIdx.x, t = threadIdx.x;
    uint4 c = *reinterpret_cast<const uint4*>(countsT + (size_t)j * KPART + t * 4);
    red[t] = c.x + c.y + c.z + c.w;
    __syncthreads();
    for (int s = 128; s > 0; s >>= 1) {
        if (t < s) red[t] += red[t + s];
        __syncthreads();
    }
    if (t == 0) btot[j] = red[0];
}

__global__ __launch_bounds__(256) void k_scanC(const unsigned* __restrict__ countsT,
                                               const unsigned* __restrict__ btot,
                                               unsigned* __restrict__ bbase,   // [NB]
                                               unsigned* __restrict__ baseT,   // [NB][KPART]
                                               int NB) {
    __shared__ unsigned red[256];
    __shared__ unsigned arr[256];
    __shared__ unsigned sBase;
    int j = blockIdx.x, t = threadIdx.x;

    // ---- bucketBase[j] = sum_{k<j} btot[k]  (masked reduce, no scanB kernel) ----
    unsigned v = 0;
    if (t < j) v += btot[t];
    if (t + 256 < j) v += btot[t + 256];
    red[t] = v;
    __syncthreads();
    for (int s = 128; s > 0; s >>= 1) {
        if (t < s) red[t] += red[t + s];
        __syncthreads();
    }
    if (t == 0) { sBase = red[0]; bbase[j] = red[0]; }

    // ---- row exclusive scan over the KPART block-counts ----
    uint4 c = *reinterpret_cast<const uint4*>(countsT + (size_t)j * KPART + t * 4);
    unsigned own = c.x + c.y + c.z + c.w;
    arr[t] = own;
    __syncthreads();
    for (int off = 1; off < 256; off <<= 1) {
        unsigned add = (t >= off) ? arr[t - off] : 0u;
        __syncthreads();
        arr[t] += add;
        __syncthreads();
    }
    unsigned base = sBase + (arr[t] - own);
    uint4 o;
    o.x = base;
    o.y = base + c.x;
    o.z = base + c.x + c.y;
    o.w = base + c.x + c.y + c.z;
    *reinterpret_cast<uint4*>(baseT + (size_t)j * KPART + t * 4) = o;
}

__global__ __launch_bounds__(256) void k_part(const int* __restrict__ src,
                                              const int* __restrict__ dst,
                                              const unsigned* __restrict__ baseT,
                                              unsigned* __restrict__ sorted,
                                              int E, int NB, int CH) {
    __shared__ unsigned base[512];
    __shared__ unsigned rank[512];
    for (int j = threadIdx.x; j < NB; j += 256) {
        base[j] = baseT[(size_t)j * KPART + blockIdx.x];
        rank[j] = 0;
    }
    __syncthreads();
    int s = blockIdx.x * CH, e = min(E, s + CH);
    int e4 = s + (((e - s) >> 2) << 2);
    for (int i = s + (int)threadIdx.x * 4; i < e4; i += 1024) {
        int4 dv = *reinterpret_cast<const int4*>(dst + i);
        int4 sv = *reinterpret_cast<const int4*>(src + i);
        unsigned d, j, r;
        d = (unsigned)dv.x; j = d >> NBSHIFT; r = atomicAdd(&rank[j], 1u);
        sorted[base[j] + r] = ((d & (NLOCAL - 1u)) << SRCBITS) | (unsigned)sv.x;
        d = (unsigned)dv.y; j = d >> NBSHIFT; r = atomicAdd(&rank[j], 1u);
        sorted[base[j] + r] = ((d & (NLOCAL - 1u)) << SRCBITS) | (unsigned)sv.y;
        d = (unsigned)dv.z; j = d >> NBSHIFT; r = atomicAdd(&rank[j], 1u);
        sorted[base[j] + r] = ((d & (NLOCAL - 1u)) << SRCBITS) | (unsigned)sv.z;
        d = (unsigned)dv.w; j = d >> NBSHIFT; r = atomicAdd(&rank[j], 1u);
        sorted[base[j] + r] = ((d & (NLOCAL - 1u)) << SRCBITS) | (unsigned)sv.w;
    }
    for (int i = e4 + threadIdx.x; i < e; i += 256) {
        unsigned d = (unsigned)dst[i];
        unsigned j = d >> NBSHIFT;
        unsigned r = atomicAdd(&rank[j], 1u);
        sorted[base[j] + r] = ((d & (NLOCAL - 1u)) << SRCBITS) | (unsigned)src[i];
    }
}

__global__ __launch_bounds__(1024) void k_deg(const unsigned* __restrict__ sorted,
                                              const unsigned* __restrict__ bbase,
                                              const unsigned* __restrict__ btot,
                                              const float* __restrict__ h,
                                              float* __restrict__ dinv,
                                              float* __restrict__ g,
                                              int N) {
    __shared__ unsigned acc[NLOCAL];
    int j = blockIdx.x, t = threadIdx.x;
    if (t < NLOCAL) acc[t] = 0;
    __syncthreads();
    unsigned s0 = bbase[j], e0 = s0 + btot[j];
    for (unsigned i = s0 + t; i < e0; i += 1024)
        atomicAdd(&acc[sorted[i] >> SRCBITS], 1u);
    __syncthreads();
    if (t < NLOCAL) {
        int n = (j << NBSHIFT) + t;
        if (n < N) {
            float di = rsqrtf((float)(acc[t] + 1u));   // +1 self-loop
            dinv[n] = di;
            g[n]    = di * h[n];
        }
    }
}

__global__ __launch_bounds__(1024) void k_agg(const unsigned* __restrict__ sorted,
                                              const unsigned* __restrict__ bbase,
                                              const unsigned* __restrict__ btot,
                                              const float* __restrict__ g,
                                              const float* __restrict__ dinv,
                                              const float* __restrict__ b,
                                              float* __restrict__ out,
                                              int N) {
    __shared__ float acc[NLOCAL];
    int j = blockIdx.x, t = threadIdx.x;
    if (t < NLOCAL) acc[t] = 0.0f;
    __syncthreads();
    unsigned s0 = bbase[j], e0 = s0 + btot[j];
    for (unsigned i = s0 + t; i < e0; i += 1024) {
        unsigned p = sorted[i];
        atomicAdd(&acc[p >> SRCBITS], g[p & ((1u << SRCBITS) - 1u)]);
    }
    __syncthreads();
    if (t < NLOCAL) {
        int n = (j << NBSHIFT) + t;
        if (n < N) {
            float v = dinv[n] * (acc[t] + g[n]) + b[0];
            out[n] = fmaxf(v, 0.0f) + log1pf(expf(-fabsf(v)));  // stable softplus
        }
    }
}

extern "C" void kernel_launch(void* const* d_in, const int* in_sizes, int n_in,
                              void* d_out, int out_size, void* d_ws, size_t ws_size,
                              hipStream_t stream) {
    const float* x  = (const float*)d_in[0];
    const int*   ei = (const int*)d_in[1];
    const float* W  = (const float*)d_in[2];
    const float* b  = (const float*)d_in[3];
    float* out = (float*)d_out;

    int N = in_sizes[0] / 256;
    int E = in_sizes[1] / 2;
    const int* src = ei;
    const int* dst = ei + E;

    int NB = (N + NLOCAL - 1) >> NBSHIFT;                 // 391
    int CH = (((E + KPART - 1) / KPART) + 3) & ~3;        // multiple of 4

    float*    h       = (float*)d_ws;                     // N
    float*    dinv    = h + N;                            // N
    float*    g       = dinv + N;                         // N
    unsigned* sorted  = (unsigned*)(g + N);               // E
    unsigned* countsT = sorted + E;                       // NB*KPART
    unsigned* baseT   = countsT + (size_t)NB * KPART;     // NB*KPART
    unsigned* btot    = baseT + (size_t)NB * KPART;       // NB
    unsigned* bbase   = btot + NB;                        // NB

    k_front<<<KPART, 256, 0, stream>>>(x, W, dst, h, countsT, N, E, NB, CH);
    k_scanA<<<NB, 256, 0, stream>>>(countsT, btot);
    k_scanC<<<NB, 256, 0, stream>>>(countsT, btot, bbase, baseT, NB);
    k_part <<<KPART, 256, 0, stream>>>(src, dst, baseT, sorted, E, NB, CH);
    k_deg  <<<NB, 1024, 0, stream>>>(sorted, bbase, btot, h, dinv, g, N);
    k_agg  <<<NB, 1024, 0, stream>>>(sorted, bbase, btot, g, dinv, b, out, N);
}